// Round 1
// baseline (269.288 us; speedup 1.0000x reference)
//
#include <hip/hip_runtime.h>
#include <hip/hip_bf16.h>

#define BB 8
#define SS 4096
#define DD 1024
#define LL 16
#define CH 64              // s-chunks per batch in ctx pass
#define CSZ (SS / CH)      // 64 s per chunk

typedef __attribute__((ext_vector_type(8))) short short8;
typedef __attribute__((ext_vector_type(4))) float fl4;

static __device__ __forceinline__ short f2bf(float f) {
    // round-to-nearest-even fp32 -> bf16 (inputs are finite normals; no NaN path)
    unsigned u = __float_as_uint(f);
    u += 0x7FFFu + ((u >> 16) & 1u);
    return (short)(u >> 16);
}

__global__ __launch_bounds__(256) void k_prep(const float* __restrict__ summ,
                                              short* __restrict__ summb) {
    int i = blockIdx.x * 256 + threadIdx.x;
    if (i < LL * DD) summb[i] = f2bf(summ[i]);
}

// e[b][l][s] = exp(dot(summ[l,:], mem[b,s,:]) / sqrt(D))
// One wave computes a full 16(l) x 16(s) score tile via mfma_f32_16x16x32_bf16.
// A-frag: summ[m=lane&15][k = (lane>>4)*8 + j]   (8 consecutive bf16)
// B-frag: mem[s=s0+(lane&15)][k = (lane>>4)*8 + j] (8 consecutive fp32, cvt->bf16)
// D: col(s)=lane&15, row(l)=(lane>>4)*4 + reg    [m89-verified layout]
__global__ __launch_bounds__(256) void k_scores(const float* __restrict__ mem,
                                                const short* __restrict__ summb,
                                                float* __restrict__ e) {
    int gwave = (blockIdx.x * 256 + threadIdx.x) >> 6;
    int lane  = threadIdx.x & 63;
    int b     = gwave >> 8;          // 256 s-tiles per batch (4096/16)
    int s0    = (gwave & 255) << 4;  // 16 s per tile
    int o  = lane & 15;
    int qd = lane >> 4;

    const short* arow = summb + o * DD + qd * 8;
    const float* mrow = mem + ((size_t)b * SS + (size_t)(s0 + o)) * DD + qd * 8;

    fl4 acc = {0.f, 0.f, 0.f, 0.f};
    #pragma unroll 4
    for (int k = 0; k < DD; k += 32) {
        short8 a = *(const short8*)(arow + k);
        fl4 f0 = *(const fl4*)(mrow + k);
        fl4 f1 = *(const fl4*)(mrow + k + 4);
        short8 bb;
        bb[0] = f2bf(f0[0]); bb[1] = f2bf(f0[1]);
        bb[2] = f2bf(f0[2]); bb[3] = f2bf(f0[3]);
        bb[4] = f2bf(f1[0]); bb[5] = f2bf(f1[1]);
        bb[6] = f2bf(f1[2]); bb[7] = f2bf(f1[3]);
        acc = __builtin_amdgcn_mfma_f32_16x16x32_bf16(a, bb, acc, 0, 0, 0);
    }

    const float scale = 0.03125f;  // 1/sqrt(1024)
    float* ebase = e + (size_t)b * LL * SS + s0 + o;
    #pragma unroll
    for (int r = 0; r < 4; ++r) {
        int l = qd * 4 + r;
        ebase[(size_t)l * SS] = __expf(acc[r] * scale);
    }
}

// Per batch: Z[l] = sum_s e[b][l][s];  q[b][s] = sum_l (w[l]/Z[l]) * e[b][l][s]
__global__ __launch_bounds__(256) void k_softmax_q(const float* __restrict__ e,
                                                   const float* __restrict__ w,
                                                   float* __restrict__ qout) {
    int b = blockIdx.x;
    int t = threadIdx.x;
    __shared__ float red[256];
    __shared__ float coef[LL];
    const float* eb = e + (size_t)b * LL * SS;

    int l = t >> 4, u = t & 15;
    float sum = 0.f;
    for (int s = u; s < SS; s += 16) sum += eb[(size_t)l * SS + s];
    red[t] = sum;
    __syncthreads();
    if (t < LL) {
        float z = 0.f;
        #pragma unroll
        for (int u2 = 0; u2 < 16; ++u2) z += red[t * 16 + u2];
        coef[t] = w[t] / z;
    }
    __syncthreads();
    for (int s = t; s < SS; s += 256) {
        float qv = 0.f;
        #pragma unroll
        for (int l2 = 0; l2 < LL; ++l2) qv += coef[l2] * eb[(size_t)l2 * SS + s];
        qout[(size_t)b * SS + s] = qv;
    }
}

// partial[b][ch][d] = sum_{s in chunk} q[b][s] * mem[b][s][d]
__global__ __launch_bounds__(256) void k_ctx(const float* __restrict__ mem,
                                             const float* __restrict__ qv,
                                             float* __restrict__ part) {
    int blk = blockIdx.x;            // 0..511
    int b  = blk >> 6;
    int ch = blk & 63;
    int t = threadIdx.x;
    int s0 = ch * CSZ;
    const float* mb = mem + ((size_t)b * SS + s0) * DD + t * 4;
    const float* qb = qv + (size_t)b * SS + s0;
    fl4 acc = {0.f, 0.f, 0.f, 0.f};
    #pragma unroll 8
    for (int i = 0; i < CSZ; ++i) {
        float qs = qb[i];                        // uniform -> s_load
        fl4 m4 = *(const fl4*)(mb + (size_t)i * DD);
        acc += qs * m4;
    }
    *(fl4*)(part + ((size_t)(b * CH + ch)) * DD + t * 4) = acc;
}

// out[b][d] = sum_ch partial[b][ch][d]
__global__ __launch_bounds__(256) void k_reduce(const float* __restrict__ part,
                                               float* __restrict__ out) {
    int idx = blockIdx.x * 256 + threadIdx.x;    // 0..8191
    int b = idx >> 10, d = idx & 1023;
    float s = 0.f;
    #pragma unroll 8
    for (int c = 0; c < CH; ++c) s += part[((size_t)(b * CH + c)) * DD + d];
    out[idx] = s;
}

extern "C" void kernel_launch(void* const* d_in, const int* in_sizes, int n_in,
                              void* d_out, int out_size, void* d_ws, size_t ws_size,
                              hipStream_t stream) {
    const float* mem  = (const float*)d_in[0];  // [8,4096,1024] fp32
    const float* summ = (const float*)d_in[1];  // [16,1024] fp32
    const float* w    = (const float*)d_in[2];  // [1,16] fp32
    float* out = (float*)d_out;                 // [8,1,1024] fp32

    char* ws = (char*)d_ws;
    short* summb = (short*)ws;                                   // 32 KB (pad to 64)
    float* e     = (float*)(ws + 64 * 1024);                     // 2 MB
    float* q     = (float*)(ws + 64 * 1024 + 2 * 1024 * 1024);   // 128 KB
    float* part  = (float*)(ws + 64 * 1024 + 2 * 1024 * 1024 + 128 * 1024); // 2 MB

    k_prep<<<64, 256, 0, stream>>>(summ, summb);
    k_scores<<<(BB * SS / 16) / 4, 256, 0, stream>>>(mem, summb, e);
    k_softmax_q<<<BB, 256, 0, stream>>>(e, w, q);
    k_ctx<<<BB * CH, 256, 0, stream>>>(mem, q, part);
    k_reduce<<<(BB * DD) / 256, 256, 0, stream>>>(part, out);
}

// Round 2
// 229.282 us; speedup vs baseline: 1.1745x; 1.1745x over previous
//
#include <hip/hip_runtime.h>
#include <hip/hip_bf16.h>

#define BB 8
#define SS 4096
#define DD 1024
#define LL 16

typedef __attribute__((ext_vector_type(8))) short short8;
typedef __attribute__((ext_vector_type(4))) float fl4;

static __device__ __forceinline__ short f2bf(float f) {
    // round-to-nearest-even fp32 -> bf16 (inputs finite, no NaN path needed)
    unsigned u = __float_as_uint(f);
    u += 0x7FFFu + ((u >> 16) & 1u);
    return (short)(u >> 16);
}

__global__ __launch_bounds__(256) void k_prep(const float* __restrict__ summ,
                                              short* __restrict__ summb) {
    int i = blockIdx.x * 256 + threadIdx.x;
    if (i < LL * DD) summb[i] = f2bf(summ[i]);
}

// e[b][l][s] = exp(dot(summ[l,:], mem[b,s,:]) / sqrt(D))
// One wave computes a 16(l) x 16(s) tile via mfma_f32_16x16x32_bf16.
// D layout: col(s)=lane&15, row(l)=(lane>>4)*4+reg  [m89-verified]
__global__ __launch_bounds__(256) void k_scores(const float* __restrict__ mem,
                                                const short* __restrict__ summb,
                                                float* __restrict__ e) {
    int gwave = (blockIdx.x * 256 + threadIdx.x) >> 6;
    int lane  = threadIdx.x & 63;
    int b     = gwave >> 8;          // 256 s-tiles per batch
    int s0    = (gwave & 255) << 4;
    int o  = lane & 15;
    int qd = lane >> 4;

    const short* arow = summb + o * DD + qd * 8;
    const float* mrow = mem + ((size_t)b * SS + (size_t)(s0 + o)) * DD + qd * 8;

    fl4 acc = {0.f, 0.f, 0.f, 0.f};
    #pragma unroll 8
    for (int k = 0; k < DD; k += 32) {
        short8 a = *(const short8*)(arow + k);
        fl4 f0 = *(const fl4*)(mrow + k);
        fl4 f1 = *(const fl4*)(mrow + k + 4);
        short8 bb;
        bb[0] = f2bf(f0[0]); bb[1] = f2bf(f0[1]);
        bb[2] = f2bf(f0[2]); bb[3] = f2bf(f0[3]);
        bb[4] = f2bf(f1[0]); bb[5] = f2bf(f1[1]);
        bb[6] = f2bf(f1[2]); bb[7] = f2bf(f1[3]);
        acc = __builtin_amdgcn_mfma_f32_16x16x32_bf16(a, bb, acc, 0, 0, 0);
    }

    const float scale = 0.03125f;  // 1/sqrt(1024)
    float* ebase = e + (size_t)b * LL * SS + s0 + o;
    #pragma unroll
    for (int r = 0; r < 4; ++r) {
        int l = qd * 4 + r;
        ebase[(size_t)l * SS] = __expf(acc[r] * scale);
    }
}

// Per batch b (one 1024-thread block): Z[l] = sum_s e[b][l][s];
// q[b][s] = sum_l (w[l]/Z[l]) * e[b][l][s]
__global__ __launch_bounds__(1024) void k_softmax_q(const float* __restrict__ e,
                                                    const float* __restrict__ w,
                                                    float* __restrict__ qout) {
    int b = blockIdx.x;
    int t = threadIdx.x;           // 1024 = 16 waves; wave id == l
    int l = t >> 6, u = t & 63;
    __shared__ float coef[LL];
    const float* eb = e + (size_t)b * LL * SS;

    float sum = 0.f;
    #pragma unroll 8
    for (int s = u; s < SS; s += 64) sum += eb[(size_t)l * SS + s];
    #pragma unroll
    for (int m = 32; m >= 1; m >>= 1) sum += __shfl_xor(sum, m, 64);
    if (u == 0) coef[l] = w[l] / sum;
    __syncthreads();

    float c[LL];
    #pragma unroll
    for (int i = 0; i < LL; ++i) c[i] = coef[i];
    #pragma unroll
    for (int s = t; s < SS; s += 1024) {
        float qv = 0.f;
        #pragma unroll
        for (int l2 = 0; l2 < LL; ++l2) qv += c[l2] * eb[(size_t)l2 * SS + s];
        qout[(size_t)b * SS + s] = qv;
    }
}

// out[b][d] += sum_{s in 64-row chunk} q[b][s] * mem[b][s][d]   (atomic epilogue)
__global__ __launch_bounds__(256) void k_ctx(const float* __restrict__ mem,
                                             const float* __restrict__ qv,
                                             float* __restrict__ out) {
    int blk = blockIdx.x;            // 512 = 8 b x 64 chunks
    int b  = blk >> 6;
    int ch = blk & 63;
    int t = threadIdx.x;
    int s0 = ch * 64;
    const float* mb = mem + ((size_t)b * SS + s0) * DD + t * 4;
    const float* qb = qv + (size_t)b * SS + s0;

    __shared__ float qs[64];
    if (t < 64) qs[t] = qb[t];
    __syncthreads();

    fl4 acc = {0.f, 0.f, 0.f, 0.f};
    #pragma unroll 8
    for (int i = 0; i < 64; ++i) {
        fl4 m4 = *(const fl4*)(mb + (size_t)i * DD);
        acc += qs[i] * m4;
    }
    float* op = out + (size_t)b * DD + t * 4;
    atomicAdd(op + 0, acc[0]);
    atomicAdd(op + 1, acc[1]);
    atomicAdd(op + 2, acc[2]);
    atomicAdd(op + 3, acc[3]);
}

extern "C" void kernel_launch(void* const* d_in, const int* in_sizes, int n_in,
                              void* d_out, int out_size, void* d_ws, size_t ws_size,
                              hipStream_t stream) {
    const float* mem  = (const float*)d_in[0];  // [8,4096,1024] fp32
    const float* summ = (const float*)d_in[1];  // [16,1024] fp32
    const float* w    = (const float*)d_in[2];  // [1,16] fp32
    float* out = (float*)d_out;                 // [8,1024] fp32

    char* ws = (char*)d_ws;
    short* summb = (short*)ws;                                   // 32 KB (pad to 64)
    float* e     = (float*)(ws + 64 * 1024);                     // 2 MB
    float* q     = (float*)(ws + 64 * 1024 + 2 * 1024 * 1024);   // 128 KB

    hipMemsetAsync(out, 0, (size_t)out_size * sizeof(float), stream);
    k_prep<<<64, 256, 0, stream>>>(summ, summb);
    k_scores<<<(BB * SS / 16) / 4, 256, 0, stream>>>(mem, summb, e);
    k_softmax_q<<<BB, 1024, 0, stream>>>(e, w, q);
    k_ctx<<<BB * 64, 256, 0, stream>>>(mem, q, out);
}

// Round 3
// 219.713 us; speedup vs baseline: 1.2256x; 1.0436x over previous
//
#include <hip/hip_runtime.h>
#include <hip/hip_bf16.h>

#define BB 8
#define SS 4096
#define DD 1024
#define LL 16

typedef __attribute__((ext_vector_type(8))) short short8;
typedef __attribute__((ext_vector_type(4))) float fl4;

static __device__ __forceinline__ short f2bf(float f) {
    // round-to-nearest-even fp32 -> bf16 (inputs finite, no NaN path needed)
    unsigned u = __float_as_uint(f);
    u += 0x7FFFu + ((u >> 16) & 1u);
    return (short)(u >> 16);
}

// Setup: summ -> bf16; zero Z (atomic target) and out (atomic target).
__global__ __launch_bounds__(256) void k_prep(const float* __restrict__ summ,
                                              short* __restrict__ summb,
                                              float* __restrict__ Z,
                                              float* __restrict__ out) {
    int i = blockIdx.x * 256 + threadIdx.x;   // 64 blocks -> 16384 threads
    if (i < LL * DD) summb[i] = f2bf(summ[i]);
    if (i < BB * LL) Z[i] = 0.f;
    if (i < BB * DD) out[i] = 0.f;
}

// Pass 1: e[b][s][l] = exp(dot(summ[l,:], mem[b,s,:]) / 32)  and
//         Z[b][l] += sum_s e  (per-block partial via shuffle+LDS, 16 atomics/block)
// One wave = one 16(l) x 16(s) tile via mfma_f32_16x16x32_bf16.
// D layout: col(s)=lane&15, row(l)=(lane>>4)*4+reg  [m89-verified]
__global__ __launch_bounds__(256) void k_scores(const float* __restrict__ mem,
                                                const short* __restrict__ summb,
                                                float* __restrict__ e,
                                                float* __restrict__ Z) {
    int widx  = threadIdx.x >> 6;
    int gwave = blockIdx.x * 4 + widx;     // 2048 waves total
    int lane  = threadIdx.x & 63;
    int b     = gwave >> 8;                // 256 s-tiles per batch
    int s0    = (gwave & 255) << 4;
    int o  = lane & 15;                    // s within tile
    int qd = lane >> 4;

    const short* arow = summb + o * DD + qd * 8;
    const float* mrow = mem + ((size_t)b * SS + (size_t)(s0 + o)) * DD + qd * 8;

    fl4 acc = {0.f, 0.f, 0.f, 0.f};
    #pragma unroll 8
    for (int k = 0; k < DD; k += 32) {
        short8 a = *(const short8*)(arow + k);
        fl4 f0 = *(const fl4*)(mrow + k);
        fl4 f1 = *(const fl4*)(mrow + k + 4);
        short8 bb;
        bb[0] = f2bf(f0[0]); bb[1] = f2bf(f0[1]);
        bb[2] = f2bf(f0[2]); bb[3] = f2bf(f0[3]);
        bb[4] = f2bf(f1[0]); bb[5] = f2bf(f1[1]);
        bb[6] = f2bf(f1[2]); bb[7] = f2bf(f1[3]);
        acc = __builtin_amdgcn_mfma_f32_16x16x32_bf16(a, bb, acc, 0, 0, 0);
    }

    const float scale = 0.03125f;  // 1/sqrt(1024)
    float ev[4];
    float* ebase = e + ((size_t)b * SS + s0) * LL;   // [b][s][l] layout
    #pragma unroll
    for (int r = 0; r < 4; ++r) {
        ev[r] = __expf(acc[r] * scale);
        ebase[o * LL + qd * 4 + r] = ev[r];          // e[b][s0+o][qd*4+r]
    }

    // Sum over the 16 s (o) within each qd group: xor masks 1,2,4,8 stay in-group.
    #pragma unroll
    for (int r = 0; r < 4; ++r) {
        float v = ev[r];
        v += __shfl_xor(v, 1, 64);
        v += __shfl_xor(v, 2, 64);
        v += __shfl_xor(v, 4, 64);
        v += __shfl_xor(v, 8, 64);
        ev[r] = v;
    }
    __shared__ float zp[4][LL];
    if (o == 0) {
        #pragma unroll
        for (int r = 0; r < 4; ++r) zp[widx][qd * 4 + r] = ev[r];
    }
    __syncthreads();
    int t = threadIdx.x;
    if (t < LL) {
        float v = zp[0][t] + zp[1][t] + zp[2][t] + zp[3][t];
        atomicAdd(&Z[b * LL + t], v);   // all 4 waves share b (256 tiles/b, 4 | 256)
    }
}

// Pass 2: coef[l] = w[l]/Z[b][l];  q[s] = sum_l coef[l]*e[b][s][l];
//         out[b][d] += sum_{s in chunk} q[s] * mem[b][s][d]
__global__ __launch_bounds__(256) void k_ctx(const float* __restrict__ mem,
                                             const float* __restrict__ e,
                                             const float* __restrict__ Z,
                                             const float* __restrict__ w,
                                             float* __restrict__ out) {
    int blk = blockIdx.x;            // 512 = 8 b x 64 chunks
    int b  = blk >> 6;
    int ch = blk & 63;
    int t = threadIdx.x;
    int s0 = ch * 64;

    __shared__ float coef[LL];
    __shared__ float qs[64];
    if (t < LL) coef[t] = w[t] / Z[b * LL + t];
    __syncthreads();
    if (t < 64) {
        const float* ep = e + ((size_t)b * SS + s0 + t) * LL;  // 64 B/thread, coalesced
        float qv = 0.f;
        #pragma unroll
        for (int l = 0; l < LL; ++l) qv += coef[l] * ep[l];
        qs[t] = qv;
    }
    __syncthreads();

    const float* mb = mem + ((size_t)b * SS + s0) * DD + t * 4;
    fl4 acc = {0.f, 0.f, 0.f, 0.f};
    #pragma unroll 8
    for (int i = 0; i < 64; ++i) {
        fl4 m4 = *(const fl4*)(mb + (size_t)i * DD);
        acc += qs[i] * m4;
    }
    float* op = out + (size_t)b * DD + t * 4;
    atomicAdd(op + 0, acc[0]);
    atomicAdd(op + 1, acc[1]);
    atomicAdd(op + 2, acc[2]);
    atomicAdd(op + 3, acc[3]);
}

extern "C" void kernel_launch(void* const* d_in, const int* in_sizes, int n_in,
                              void* d_out, int out_size, void* d_ws, size_t ws_size,
                              hipStream_t stream) {
    const float* mem  = (const float*)d_in[0];  // [8,4096,1024] fp32
    const float* summ = (const float*)d_in[1];  // [16,1024] fp32
    const float* w    = (const float*)d_in[2];  // [1,16] fp32
    float* out = (float*)d_out;                 // [8,1024] fp32

    char* ws = (char*)d_ws;
    short* summb = (short*)ws;                                   // 32 KB (pad to 64)
    float* Z     = (float*)(ws + 64 * 1024);                     // 512 B (pad to 4K)
    float* e     = (float*)(ws + 68 * 1024);                     // 2 MB [b][s][l]

    k_prep<<<64, 256, 0, stream>>>(summ, summb, Z, out);
    k_scores<<<(BB * SS / 16) / 4, 256, 0, stream>>>(mem, summb, e, Z);
    k_ctx<<<BB * 64, 256, 0, stream>>>(mem, e, Z, w, out);
}